// Round 1
// baseline (155.715 us; speedup 1.0000x reference)
//
#include <hip/hip_runtime.h>
#include <math.h>

#define Z   4
#define N1  192
#define NN  384          // n1 + n2
#define C   16
#define NB  10
#define H   12

// ---------------------------------------------------------------------------
// helpers
// ---------------------------------------------------------------------------
__device__ __forceinline__ float3 load_xyz(const float* __restrict__ xyz1,
                                           const float* __restrict__ xyz2,
                                           int z, int node) {
    const float* p = (node < N1) ? (xyz1 + (z * N1 + node) * 3)
                                 : (xyz2 + (z * N1 + (node - N1)) * 3);
    return make_float3(p[0], p[1], p[2]);
}

// ---------------------------------------------------------------------------
// Kernel 1: T[z,b,h,i] = (Y0/sqrt(H)) * sum_j W_rad_out[h, i*16+j] * x[z,b,j]
// grid = Z*NN blocks, 192 threads (one per (h,i)). Also zeros the s accumulator.
// ---------------------------------------------------------------------------
__global__ void k1_precompute_T(const float* __restrict__ in1,
                                const float* __restrict__ in2,
                                const float* __restrict__ Wro,
                                float* __restrict__ T,
                                float* __restrict__ s_acc) {
    const int bid = blockIdx.x;          // z*NN + b
    const int z = bid / NN, b = bid % NN;
    const int t = threadIdx.x;           // 0..191  -> h = t>>4, i = t&15

    __shared__ float xl[C];
    if (t < C) {
        const float* xp = (b < N1) ? (in1 + (z * N1 + b) * C)
                                   : (in2 + (z * N1 + (b - N1)) * C);
        xl[t] = xp[t];
    }
    if (bid == 0 && t < Z * C) s_acc[t] = 0.0f;   // zero accumulator (ws is poisoned)
    __syncthreads();

    const int h = t >> 4, i = t & 15;
    const float* w = Wro + h * (C * C) + i * C;
    float acc = 0.0f;
    #pragma unroll
    for (int j = 0; j < C; ++j) acc += w[j] * xl[j];

    // Y0 = 1/(2*sqrt(pi)) ; 1/sqrt(H)=1/sqrt(12)
    const float scale = 0.28209479177387814f * 0.2886751345948129f;
    T[bid * (H * C) + t] = acc * scale;
}

// ---------------------------------------------------------------------------
// Kernel 2: per (z,a) block: y[i] = sum_b sum_h silu(basis(d_ab)@W1)[h] * T[z,b,h,i]
// then abs, mask, atomic-accumulate into s[z,i].
// 128 threads = 2 waves; wave w covers b in [w*192, w*192+192), 3 b's per lane.
// ---------------------------------------------------------------------------
__global__ __launch_bounds__(128) void k2_pairs(const float* __restrict__ xyz1,
                                                const float* __restrict__ xyz2,
                                                const int* __restrict__ mask,
                                                const float* __restrict__ Wr1,
                                                const float* __restrict__ T,
                                                float* __restrict__ s_acc) {
    const int bid = blockIdx.x;          // z*NN + a
    const int z = bid / NN, a = bid % NN;
    const int tid = threadIdx.x;
    const int lane = tid & 63, wv = tid >> 6;

    __shared__ float W1s[NB * H];        // W_rad1 * (1/sqrt(NB))
    __shared__ float part[2][C];
    if (tid < NB * H) W1s[tid] = Wr1[tid] * 0.31622776601683794f;
    __syncthreads();

    const float3 pa = load_xyz(xyz1, xyz2, z, a);

    float y[C];
    #pragma unroll
    for (int i = 0; i < C; ++i) y[i] = 0.0f;

    const float invSigma = 1.125f;                 // 1/(0.8*10/9)
    const float invGN    = 0.7027283689263438f;    // 1/1.423085244900308

    for (int s = 0; s < 3; ++s) {
        const int b = wv * 192 + s * 64 + lane;    // covers [0,384) exactly
        const float3 pb = load_xyz(xyz1, xyz2, z, b);
        const float dx = pa.x - pb.x, dy = pa.y - pb.y, dz = pa.z - pb.z;
        const float d = sqrtf(dx * dx + dy * dy + dz * dz + 1e-12f);

        float basis[NB];
        #pragma unroll
        for (int k = 0; k < NB; ++k) {
            const float u = (d - (float)k * (10.0f / 9.0f)) * invSigma;
            basis[k] = __expf(-u * u) * invGN;
        }

        float hm[H];
        #pragma unroll
        for (int h = 0; h < H; ++h) {
            float acc = 0.0f;
            #pragma unroll
            for (int k = 0; k < NB; ++k) acc += basis[k] * W1s[k * H + h];
            hm[h] = acc / (1.0f + __expf(-acc));   // silu
        }

        const float4* tp = (const float4*)(T + (z * NN + b) * (H * C));
        #pragma unroll
        for (int h = 0; h < H; ++h) {
            #pragma unroll
            for (int q = 0; q < 4; ++q) {
                const float4 t4 = tp[h * 4 + q];
                y[q * 4 + 0] += hm[h] * t4.x;
                y[q * 4 + 1] += hm[h] * t4.y;
                y[q * 4 + 2] += hm[h] * t4.z;
                y[q * 4 + 3] += hm[h] * t4.w;
            }
        }
    }

    // reduce y[16] across the 64 lanes of each wave (butterfly)
    #pragma unroll
    for (int i = 0; i < C; ++i) {
        float v = y[i];
        #pragma unroll
        for (int ofs = 32; ofs >= 1; ofs >>= 1) v += __shfl_xor(v, ofs, 64);
        y[i] = v;
    }
    if (lane < C) part[wv][lane] = y[lane];
    __syncthreads();

    if (tid < C) {
        float v = part[0][tid] + part[1][tid];
        v = fabsf(v);
        if (mask[z * NN + a] == 0) v = 0.0f;
        atomicAdd(&s_acc[z * C + tid], v);
    }
}

// ---------------------------------------------------------------------------
// Kernel 3: normalize (ddof=1) + fc3 + leaky_relu + fc2 + sigmoid -> out[Z]
// ---------------------------------------------------------------------------
__global__ void k3_head(const float* __restrict__ s_acc,
                        const float* __restrict__ Wfc3,
                        const float* __restrict__ Wfc2,
                        float* __restrict__ out) {
    const int t = threadIdx.x;
    if (t >= Z) return;
    const float* s = s_acc + t * C;

    float v[C];
    float mean = 0.0f;
    #pragma unroll
    for (int i = 0; i < C; ++i) { v[i] = s[i]; mean += v[i]; }
    mean *= (1.0f / C);
    float var = 0.0f;
    #pragma unroll
    for (int i = 0; i < C; ++i) { const float d = v[i] - mean; var += d * d; }
    const float sd = sqrtf(var / (float)(C - 1)) + 1e-6f;
    #pragma unroll
    for (int i = 0; i < C; ++i) v[i] = (v[i] - mean) / sd;

    float o = 0.0f;
    #pragma unroll
    for (int k = 0; k < C; ++k) {
        float h3 = 0.0f;
        #pragma unroll
        for (int i = 0; i < C; ++i) h3 += v[i] * Wfc3[i * C + k];
        h3 *= 0.25f;                               // / sqrt(C)
        h3 = (h3 > 0.0f) ? h3 : 0.01f * h3;        // leaky_relu
        o += h3 * Wfc2[k];
    }
    o *= 0.25f;                                    // / sqrt(C)
    out[t] = 1.0f / (1.0f + __expf(-o));
}

// ---------------------------------------------------------------------------
extern "C" void kernel_launch(void* const* d_in, const int* in_sizes, int n_in,
                              void* d_out, int out_size, void* d_ws, size_t ws_size,
                              hipStream_t stream) {
    const float* in1  = (const float*)d_in[0];
    const float* in2  = (const float*)d_in[1];
    const float* xyz1 = (const float*)d_in[2];
    const float* xyz2 = (const float*)d_in[3];
    const int*   mask = (const int*)d_in[4];
    const float* Wr1  = (const float*)d_in[5];
    const float* Wro  = (const float*)d_in[6];
    const float* Wfc3 = (const float*)d_in[7];
    const float* Wfc2 = (const float*)d_in[8];
    float* out = (float*)d_out;

    float* T     = (float*)d_ws;                 // Z*NN*H*C floats = 1.18 MB
    float* s_acc = T + Z * NN * H * C;           // Z*C floats

    k1_precompute_T<<<Z * NN, 192, 0, stream>>>(in1, in2, Wro, T, s_acc);
    k2_pairs<<<Z * NN, 128, 0, stream>>>(xyz1, xyz2, mask, Wr1, T, s_acc);
    k3_head<<<1, 64, 0, stream>>>(s_acc, Wfc3, Wfc2, out);
}

// Round 2
// 103.549 us; speedup vs baseline: 1.5038x; 1.5038x over previous
//
#include <hip/hip_runtime.h>
#include <math.h>

#define Z     4
#define N1    192
#define NN    384          // n1 + n2
#define C     16
#define NB    10
#define H     12
#define ATILE 4
#define NAT   (NN / ATILE) // 96
#define SPLIT 3            // b-splits: 3 * 128 threads = 384 b's

// ---------------------------------------------------------------------------
__device__ __forceinline__ float3 load_xyz(const float* __restrict__ xyz1,
                                           const float* __restrict__ xyz2,
                                           int z, int node) {
    const float* p = (node < N1) ? (xyz1 + (z * N1 + node) * 3)
                                 : (xyz2 + (z * N1 + (node - N1)) * 3);
    return make_float3(p[0], p[1], p[2]);
}

// ---------------------------------------------------------------------------
// Kernel 1: T[z,b,h,i] = (Y0/sqrt(H)) * sum_j W_rad_out[h, i*16+j] * x[z,b,j]
// grid = Z*NN blocks, 192 threads (one per (h,i)).
// ---------------------------------------------------------------------------
__global__ void k1_precompute_T(const float* __restrict__ in1,
                                const float* __restrict__ in2,
                                const float* __restrict__ Wro,
                                float* __restrict__ T) {
    const int bid = blockIdx.x;          // z*NN + b
    const int z = bid / NN, b = bid % NN;
    const int t = threadIdx.x;           // 0..191  -> h = t>>4, i = t&15

    __shared__ float xl[C];
    if (t < C) {
        const float* xp = (b < N1) ? (in1 + (z * N1 + b) * C)
                                   : (in2 + (z * N1 + (b - N1)) * C);
        xl[t] = xp[t];
    }
    __syncthreads();

    const int h = t >> 4, i = t & 15;
    const float* w = Wro + h * (C * C) + i * C;
    float acc = 0.0f;
    #pragma unroll
    for (int j = 0; j < C; ++j) acc += w[j] * xl[j];

    // Y0 = 1/(2*sqrt(pi)) ; 1/sqrt(12)
    const float scale = 0.28209479177387814f * 0.2886751345948129f;
    T[bid * (H * C) + t] = acc * scale;
}

// ---------------------------------------------------------------------------
// Kernel 2: block = (z, tile of 4 a's, 1-of-3 b-split). 128 threads, 1 b/lane.
// y[a][i] partial over this block's 128 b's -> fold-reduce -> partial[bid][64].
// ---------------------------------------------------------------------------
__global__ __launch_bounds__(128) void k2_pairs(const float* __restrict__ xyz1,
                                                const float* __restrict__ xyz2,
                                                const float* __restrict__ Wr1,
                                                const float* __restrict__ T,
                                                float* __restrict__ partial) {
    const int bid = blockIdx.x;          // (z*NAT + at)*SPLIT + sp
    const int sp  = bid % SPLIT;
    const int za  = bid / SPLIT;
    const int z   = za / NAT, at = za % NAT;
    const int a0  = at * ATILE;
    const int tid = threadIdx.x;
    const int lane = tid & 63, wv = tid >> 6;
    const int b = sp * 128 + tid;        // this lane's b

    __shared__ float W1s[NB * H];        // W_rad1 * (1/sqrt(NB))
    __shared__ float red[2][64];
    if (tid < NB * H) W1s[tid] = Wr1[tid] * 0.31622776601683794f;
    __syncthreads();

    const float3 pb = load_xyz(xyz1, xyz2, z, b);

    float v[ATILE * C];                  // y accumulators, pos = a_off*16 + i
    #pragma unroll
    for (int p = 0; p < ATILE * C; ++p) v[p] = 0.0f;

    const float invSigma = 1.125f;                 // 1/(0.8*10/9)
    const float invGN    = 0.7027283689263438f;    // 1/1.423085244900308
    const float4* tp = (const float4*)(T + (z * NN + b) * (H * C));

    #pragma unroll
    for (int pass = 0; pass < 2; ++pass) {         // 2 a's per pass (VGPR cap)
        float hm[2][H];
        #pragma unroll
        for (int aa = 0; aa < 2; ++aa) {
            const int a = a0 + pass * 2 + aa;
            const float3 pa = load_xyz(xyz1, xyz2, z, a);
            const float dx = pa.x - pb.x, dy = pa.y - pb.y, dz = pa.z - pb.z;
            const float d = sqrtf(dx * dx + dy * dy + dz * dz + 1e-12f);

            float basis[NB];
            #pragma unroll
            for (int k = 0; k < NB; ++k) {
                const float u = (d - (float)k * (10.0f / 9.0f)) * invSigma;
                basis[k] = __expf(-u * u) * invGN;
            }
            #pragma unroll
            for (int h = 0; h < H; ++h) {
                float acc = 0.0f;
                #pragma unroll
                for (int k = 0; k < NB; ++k) acc += basis[k] * W1s[k * H + h];
                hm[aa][h] = acc / (1.0f + __expf(-acc));   // silu
            }
        }

        #pragma unroll
        for (int h = 0; h < H; ++h) {
            const float4 t0 = tp[h * 4 + 0];
            const float4 t1 = tp[h * 4 + 1];
            const float4 t2 = tp[h * 4 + 2];
            const float4 t3 = tp[h * 4 + 3];
            #pragma unroll
            for (int aa = 0; aa < 2; ++aa) {
                const float f = hm[aa][h];
                const int o = (pass * 2 + aa) * C;
                v[o +  0] += f * t0.x;  v[o +  1] += f * t0.y;
                v[o +  2] += f * t0.z;  v[o +  3] += f * t0.w;
                v[o +  4] += f * t1.x;  v[o +  5] += f * t1.y;
                v[o +  6] += f * t1.z;  v[o +  7] += f * t1.w;
                v[o +  8] += f * t2.x;  v[o +  9] += f * t2.y;
                v[o + 10] += f * t2.z;  v[o + 11] += f * t2.w;
                v[o + 12] += f * t3.x;  v[o + 13] += f * t3.y;
                v[o + 14] += f * t3.z;  v[o + 15] += f * t3.w;
            }
        }
    }

    // value-halving fold across the 64 lanes: after 6 steps lane l holds the
    // wave-sum for position bitrev6(l). All indices compile-time (no scratch).
    #pragma unroll
    for (int k = 0; k < 6; ++k) {
        const int m = 32 >> k;
        const int bsel = (lane >> k) & 1;
        #pragma unroll
        for (int j = 0; j < m; ++j) {
            const float lo = v[j], hi = v[m + j];
            const float sendv = bsel ? lo : hi;          // partner's needed half
            const float recv = __shfl_xor(sendv, 1 << k, 64);
            v[j] = (bsel ? hi : lo) + recv;
        }
    }
    const int l = lane;
    const int pos = ((l & 1) << 5) | ((l & 2) << 3) | ((l & 4) << 1) |
                    ((l & 8) >> 1) | ((l & 16) >> 3) | ((l & 32) >> 5);
    red[wv][pos] = v[0];
    __syncthreads();
    if (tid < 64) partial[bid * 64 + tid] = red[0][tid] + red[1][tid];
}

// ---------------------------------------------------------------------------
// Kernel 3: per z: sum splits, abs, mask, sum over a -> s[16];
// then normalize (ddof=1) + fc3 + leaky_relu + fc2 + sigmoid.
// grid = Z blocks, 256 threads.
// ---------------------------------------------------------------------------
__global__ __launch_bounds__(256) void k3_head(const float* __restrict__ partial,
                                               const int* __restrict__ mask,
                                               const float* __restrict__ Wfc3,
                                               const float* __restrict__ Wfc2,
                                               float* __restrict__ out) {
    const int z = blockIdx.x;
    const int t = threadIdx.x;           // 256 = 16 chunks x 16 i
    const int i = t & 15, ch = t >> 4;

    __shared__ float red[16][17];
    __shared__ float sv[C];

    float acc = 0.0f;
    #pragma unroll
    for (int r = 0; r < 24; ++r) {       // 16 chunks * 24 = 384 a's
        const int a  = ch * 24 + r;
        const int at = a >> 2, t2 = a & 3;
        const int base = ((z * NAT + at) * SPLIT) * 64 + t2 * 16 + i;
        float val = partial[base] + partial[base + 64] + partial[base + 128];
        val = fabsf(val);
        if (mask[z * NN + a] != 0) acc += val;
    }
    red[ch][i] = acc;
    __syncthreads();
    if (t < C) {
        float s = 0.0f;
        #pragma unroll
        for (int c2 = 0; c2 < 16; ++c2) s += red[c2][t];
        sv[t] = s;
    }
    __syncthreads();

    if (t == 0) {
        float v[C];
        float mean = 0.0f;
        #pragma unroll
        for (int q = 0; q < C; ++q) { v[q] = sv[q]; mean += v[q]; }
        mean *= (1.0f / C);
        float var = 0.0f;
        #pragma unroll
        for (int q = 0; q < C; ++q) { const float d = v[q] - mean; var += d * d; }
        const float sd = sqrtf(var / (float)(C - 1)) + 1e-6f;
        #pragma unroll
        for (int q = 0; q < C; ++q) v[q] = (v[q] - mean) / sd;

        float o = 0.0f;
        #pragma unroll
        for (int k = 0; k < C; ++k) {
            float h3 = 0.0f;
            #pragma unroll
            for (int q = 0; q < C; ++q) h3 += v[q] * Wfc3[q * C + k];
            h3 *= 0.25f;                               // / sqrt(16)
            h3 = (h3 > 0.0f) ? h3 : 0.01f * h3;        // leaky_relu
            o += h3 * Wfc2[k];
        }
        o *= 0.25f;
        out[z] = 1.0f / (1.0f + __expf(-o));
    }
}

// ---------------------------------------------------------------------------
extern "C" void kernel_launch(void* const* d_in, const int* in_sizes, int n_in,
                              void* d_out, int out_size, void* d_ws, size_t ws_size,
                              hipStream_t stream) {
    const float* in1  = (const float*)d_in[0];
    const float* in2  = (const float*)d_in[1];
    const float* xyz1 = (const float*)d_in[2];
    const float* xyz2 = (const float*)d_in[3];
    const int*   mask = (const int*)d_in[4];
    const float* Wr1  = (const float*)d_in[5];
    const float* Wro  = (const float*)d_in[6];
    const float* Wfc3 = (const float*)d_in[7];
    const float* Wfc2 = (const float*)d_in[8];
    float* out = (float*)d_out;

    float* T       = (float*)d_ws;                   // Z*NN*H*C floats = 1.18 MB
    float* partial = T + Z * NN * H * C;             // Z*NAT*SPLIT*64 = 294 KB

    k1_precompute_T<<<Z * NN, 192, 0, stream>>>(in1, in2, Wro, T);
    k2_pairs<<<Z * NAT * SPLIT, 128, 0, stream>>>(xyz1, xyz2, Wr1, T, partial);
    k3_head<<<Z, 256, 0, stream>>>(partial, mask, Wfc3, Wfc2, out);
}